// Round 3
// baseline (188.784 us; speedup 1.0000x reference)
//
#include <hip/hip_runtime.h>

#define BB 4
#define TQ 512
#define TK 512
#define DQ 512
#define UU 256
#define CSC 2.8853900817779268f   // 2*log2(e), folded into projections: x = 2log2e*(q+k)
#define L2E 1.4426950408889634f
#define RQ 2   // q-rows per attn block

__device__ __forceinline__ float fexp2(float x) { return __builtin_amdgcn_exp2f(x); }
__device__ __forceinline__ float frcp(float x)  { return __builtin_amdgcn_rcpf(x); }

// C = CSC*(A @ W). A:[M,K] row-major (wave-uniform loads), W:[K,N] row-major
// (coalesced, L2-resident). Block: 512 thr = (n:256, kh:2); kh splits K, LDS combine.
// 8 A-rows per block; grid (M/8, 1, 2). Register double-buffer on W rows.
__global__ __launch_bounds__(512) void proj(
    const float* __restrict__ Aq, const float* __restrict__ Av,
    const float* __restrict__ W1, const float* __restrict__ W2,
    float* __restrict__ Cq, float* __restrict__ Ck)
{
    const float* A; const float* W; float* C;
    if (blockIdx.z == 0) { A = Aq; W = W1; C = Cq; }
    else                 { A = Av; W = W2; C = Ck; }

    const int n  = threadIdx.x;          // 0..255
    const int kh = threadIdx.y;          // 0..1 (wave-uniform: waves are 64 consecutive x)
    const int m0 = blockIdx.x * 8;
    const int kbase = kh * (DQ / 2);
    const float* a0 = A + (size_t)m0 * DQ + kbase;
    const float* w0 = W + (size_t)kbase * UU + n;

    float acc[8] = {};
    float wc[4], wn[4];
    #pragma unroll
    for (int j = 0; j < 4; j++) wc[j] = w0[(size_t)j * UU];

    for (int k = 0; k < DQ / 2; k += 4) {
        const int kp4 = (k + 4 < DQ / 2) ? (k + 4) : 0;   // clamped prefetch
        #pragma unroll
        for (int j = 0; j < 4; j++) wn[j] = w0[(size_t)(kp4 + j) * UU];
        #pragma unroll
        for (int r = 0; r < 8; r++) {
            const float4 a = *(const float4*)&a0[(size_t)r * DQ + k];  // wave-uniform
            acc[r] = fmaf(a.x, wc[0], fmaf(a.y, wc[1],
                     fmaf(a.z, wc[2], fmaf(a.w, wc[3], acc[r]))));
        }
        #pragma unroll
        for (int j = 0; j < 4; j++) wc[j] = wn[j];
    }

    __shared__ float part[8][UU];
    if (kh == 1) {
        #pragma unroll
        for (int r = 0; r < 8; r++) part[r][n] = acc[r];
    }
    __syncthreads();
    if (kh == 0) {
        #pragma unroll
        for (int r = 0; r < 8; r++)
            C[(size_t)(m0 + r) * UU + n] = CSC * (acc[r] + part[r][n]);
    }
}

// kT4[b][u/4][j][u&3] = kp[b][j][u]  -- interleaved so attn loads 4 u's per float4
__global__ __launch_bounds__(256) void transpose_k(
    const float* __restrict__ kp, float* __restrict__ kT)
{
    __shared__ float tile[32][36];   // [j-local][u-local], rows 16B-aligned
    const int b  = blockIdx.z;
    const int j0 = blockIdx.x * 32;
    const int u0 = blockIdx.y * 32;
    const int tx = threadIdx.x;   // 0..31
    const int ty = threadIdx.y;   // 0..7
    #pragma unroll
    for (int r = 0; r < 32; r += 8)
        tile[ty + r][tx] = kp[(size_t)(b * TK + j0 + ty + r) * UU + u0 + tx];
    __syncthreads();
    const float4 v = *(const float4*)&tile[tx][4 * ty];
    ((float4*)kT)[(size_t)b * (UU / 4) * TK + (size_t)(u0 / 4 + ty) * TK + j0 + tx] = v;
}

// One block per (b, RQ=2 q-rows); 512 threads, thread t = column j.
// shifted_score[r][t] = sum_u scale_u * (-2 / (1 + 2^(q+k)))  (softmax shift-invariant).
__global__ __launch_bounds__(512) void attn_softmax(
    const float* __restrict__ qp,    // [BB, TQ, UU], pre-scaled by 2log2e
    const float* __restrict__ kT,    // [BB, UU/4, TK] of float4 (interleaved u)
    const float* __restrict__ scale, // [UU]
    float* __restrict__ out)         // [BB, TQ, TK]
{
    __shared__ float redbuf[RQ][8];

    const int t  = threadIdx.x;
    const int b  = blockIdx.x >> 8;            // TQ/RQ = 256 blocks per b
    const int q0 = (blockIdx.x & 255) * RQ;

    const float*  qrow = qp + (size_t)(b * TQ + q0) * UU;          // wave-uniform
    const float4* kb4  = (const float4*)kT + (size_t)b * (UU / 4) * TK + t;

    float a0[RQ] = {}, a1[RQ] = {};   // split accumulators (even/odd pairs)
    float4 kv = kb4[0];

    #pragma unroll 2
    for (int g = 0; g < UU / 4 - 1; g++) {
        const float4 kn  = kb4[(size_t)(g + 1) * TK];   // prefetch next
        const float4 sc4 = *(const float4*)&scale[4 * g];
        float4 q4[RQ];
        #pragma unroll
        for (int r = 0; r < RQ; r++)
            q4[r] = *(const float4*)&qrow[(size_t)r * UU + 4 * g];
        #pragma unroll
        for (int r = 0; r < RQ; r++) {
            const float* qf = (const float*)&q4[r];
            const float* sf = (const float*)&sc4;
            const float* kf = (const float*)&kv;
            a0[r] = fmaf(sf[0], frcp(fmaf(-0.5f, fexp2(qf[0] + kf[0]), -0.5f)), a0[r]);
            a1[r] = fmaf(sf[1], frcp(fmaf(-0.5f, fexp2(qf[1] + kf[1]), -0.5f)), a1[r]);
            a0[r] = fmaf(sf[2], frcp(fmaf(-0.5f, fexp2(qf[2] + kf[2]), -0.5f)), a0[r]);
            a1[r] = fmaf(sf[3], frcp(fmaf(-0.5f, fexp2(qf[3] + kf[3]), -0.5f)), a1[r]);
        }
        kv = kn;
    }
    {   // peeled last group
        const int g = UU / 4 - 1;
        const float4 sc4 = *(const float4*)&scale[4 * g];
        #pragma unroll
        for (int r = 0; r < RQ; r++) {
            float4 q4 = *(const float4*)&qrow[(size_t)r * UU + 4 * g];
            const float* qf = (const float*)&q4;
            const float* sf = (const float*)&sc4;
            const float* kf = (const float*)&kv;
            a0[r] = fmaf(sf[0], frcp(fmaf(-0.5f, fexp2(qf[0] + kf[0]), -0.5f)), a0[r]);
            a1[r] = fmaf(sf[1], frcp(fmaf(-0.5f, fexp2(qf[1] + kf[1]), -0.5f)), a1[r]);
            a0[r] = fmaf(sf[2], frcp(fmaf(-0.5f, fexp2(qf[2] + kf[2]), -0.5f)), a0[r]);
            a1[r] = fmaf(sf[3], frcp(fmaf(-0.5f, fexp2(qf[3] + kf[3]), -0.5f)), a1[r]);
        }
    }

    const int wave = t >> 6, lane = t & 63;
    float s[RQ], m[RQ], p[RQ];
    #pragma unroll
    for (int r = 0; r < RQ; r++) s[r] = a0[r] + a1[r];

    // row max over 512 threads
    #pragma unroll
    for (int r = 0; r < RQ; r++) {
        float v = s[r];
        #pragma unroll
        for (int o = 32; o > 0; o >>= 1) v = fmaxf(v, __shfl_xor(v, o));
        if (lane == 0) redbuf[r][wave] = v;
    }
    __syncthreads();
    #pragma unroll
    for (int r = 0; r < RQ; r++) {
        float v = redbuf[r][0];
        #pragma unroll
        for (int w = 1; w < 8; w++) v = fmaxf(v, redbuf[r][w]);
        m[r] = v;
    }
    __syncthreads();

    // exp and row sum
    #pragma unroll
    for (int r = 0; r < RQ; r++) {
        p[r] = fexp2(L2E * (s[r] - m[r]));
        float v = p[r];
        #pragma unroll
        for (int o = 32; o > 0; o >>= 1) v += __shfl_xor(v, o);
        if (lane == 0) redbuf[r][wave] = v;
    }
    __syncthreads();
    #pragma unroll
    for (int r = 0; r < RQ; r++) {
        float v = 0.0f;
        #pragma unroll
        for (int w = 0; w < 8; w++) v += redbuf[r][w];
        const float rinv = frcp(v);
        out[(size_t)(b * TQ + q0 + r) * TK + t] = p[r] * rinv;
    }
}

extern "C" void kernel_launch(void* const* d_in, const int* in_sizes, int n_in,
                              void* d_out, int out_size, void* d_ws, size_t ws_size,
                              hipStream_t stream) {
    const float* query = (const float*)d_in[0];
    const float* value = (const float*)d_in[1];
    const float* W1    = (const float*)d_in[2];
    const float* W2    = (const float*)d_in[3];
    const float* scale = (const float*)d_in[4];
    float* out = (float*)d_out;

    float* qp = (float*)d_ws;                     // [BB,TQ,UU]  2 MB
    float* kp = qp + (size_t)BB * TQ * UU;        // [BB,TK,UU]  2 MB
    float* kT = kp + (size_t)BB * TK * UU;        // [BB,UU/4,TK] float4  2 MB

    proj<<<dim3((BB * TQ) / 8, 1, 2), dim3(256, 2), 0, stream>>>(query, value, W1, W2, qp, kp);
    transpose_k<<<dim3(TK / 32, UU / 32, BB), dim3(32, 8), 0, stream>>>(kp, kT);
    attn_softmax<<<dim3(BB * TQ / RQ), 512, 0, stream>>>(qp, kT, scale, out);
}

// Round 4
// 166.133 us; speedup vs baseline: 1.1363x; 1.1363x over previous
//
#include <hip/hip_runtime.h>

#define BB 4
#define TQ 512
#define TK 512
#define DQ 512
#define UU 256
#define KH (DQ / 2)
#define CSC 2.8853900817779268f   // 2*log2(e), folded into projections: x = 2log2e*(q+k)
#define L2E 1.4426950408889634f
#define RQ 2   // q-rows per attn block

__device__ __forceinline__ float fexp2(float x) { return __builtin_amdgcn_exp2f(x); }
__device__ __forceinline__ float frcp(float x)  { return __builtin_amdgcn_rcpf(x); }

// proj: C = CSC*(A@W).
//   z=0: query@W1 -> qp [BB*TQ, UU] row-major.
//   z=1: value@W2 -> kT  [BB][UU/4][TK] float4 (u-interleaved transposed layout).
// Block (256,2): n = tx (output col), kh = ty splits K in half (LDS combine).
// 8 rows per block. W prefetched 16 k-rows deep in registers (ping-pong).
__global__ __launch_bounds__(512) void proj(
    const float* __restrict__ Aq, const float* __restrict__ Av,
    const float* __restrict__ W1, const float* __restrict__ W2,
    float* __restrict__ qp, float* __restrict__ kT)
{
    __shared__ float part[8][UU];       // kh=1 partial sums
    __shared__ float fin[8][UU + 4];    // padded bounce buffer (z=1)

    const float* A; const float* W;
    const int z = blockIdx.z;
    if (z == 0) { A = Aq; W = W1; }
    else        { A = Av; W = W2; }

    const int n  = threadIdx.x;                                   // 0..255
    const int kh = __builtin_amdgcn_readfirstlane(threadIdx.y);   // 0..1, forced SGPR
    const int m0 = blockIdx.x * 8;
    const int kb = kh * KH;
    const float* a0 = A + (size_t)m0 * DQ + kb;   // scalar (uniform) A base
    const float* w0 = W + (size_t)kb * UU + n;

    float acc[8] = {};
    float wcur[16], wnxt[16];
    #pragma unroll
    for (int j = 0; j < 16; j++) wcur[j] = w0[(size_t)j * UU];

    for (int k0 = 0; k0 < KH; k0 += 32) {
        #pragma unroll
        for (int j = 0; j < 16; j++) wnxt[j] = w0[(size_t)(k0 + 16 + j) * UU];
        #pragma unroll
        for (int kk = 0; kk < 16; kk += 4) {
            #pragma unroll
            for (int r = 0; r < 8; r++) {
                const float4 a = *(const float4*)&a0[(size_t)r * DQ + k0 + kk];
                acc[r] = fmaf(a.x, wcur[kk + 0], fmaf(a.y, wcur[kk + 1],
                         fmaf(a.z, wcur[kk + 2], fmaf(a.w, wcur[kk + 3], acc[r]))));
            }
        }
        const int k2 = (k0 + 32 < KH) ? (k0 + 32) : k0;   // clamped (discarded) prefetch
        #pragma unroll
        for (int j = 0; j < 16; j++) wcur[j] = w0[(size_t)(k2 + j) * UU];
        #pragma unroll
        for (int kk = 0; kk < 16; kk += 4) {
            #pragma unroll
            for (int r = 0; r < 8; r++) {
                const float4 a = *(const float4*)&a0[(size_t)r * DQ + k0 + 16 + kk];
                acc[r] = fmaf(a.x, wnxt[kk + 0], fmaf(a.y, wnxt[kk + 1],
                         fmaf(a.z, wnxt[kk + 2], fmaf(a.w, wnxt[kk + 3], acc[r]))));
            }
        }
    }

    if (kh == 1) {
        #pragma unroll
        for (int r = 0; r < 8; r++) part[r][n] = acc[r];
    }
    __syncthreads();

    if (z == 0) {
        if (kh == 0) {
            #pragma unroll
            for (int r = 0; r < 8; r++)
                qp[(size_t)(m0 + r) * UU + n] = CSC * (acc[r] + part[r][n]);
        }
    } else {
        if (kh == 0) {
            #pragma unroll
            for (int r = 0; r < 8; r++) fin[r][n] = CSC * (acc[r] + part[r][n]);
        }
        __syncthreads();
        // bounce to kT4[b][u/4][j][4]; 512 threads x 1 float4 each
        const int t  = threadIdx.y * 256 + threadIdx.x;
        const int jl = t & 7;            // lanes vary j fastest -> 128B chunks
        const int u4 = t >> 3;           // 0..63
        const int b  = m0 >> 9;
        const int j0 = m0 & 511;
        const float4 v = *(const float4*)&fin[jl][u4 * 4];
        ((float4*)kT)[(size_t)b * (UU / 4) * TK + (size_t)u4 * TK + (j0 + jl)] = v;
    }
}

// One block per (b, RQ=2 q-rows); 512 threads, thread t = column j.
// shifted_score[r][t] = sum_u scale_u * (-2 / (1 + 2^(q+k)))  (softmax shift-invariant).
__global__ __launch_bounds__(512) void attn_softmax(
    const float* __restrict__ qp,    // [BB, TQ, UU], pre-scaled by 2log2e
    const float* __restrict__ kT,    // [BB, UU/4, TK] of float4 (interleaved u)
    const float* __restrict__ scale, // [UU]
    float* __restrict__ out)         // [BB, TQ, TK]
{
    __shared__ float redbuf[RQ][8];

    const int t  = threadIdx.x;
    const int b  = blockIdx.x >> 8;            // TQ/RQ = 256 blocks per b
    const int q0 = (blockIdx.x & 255) * RQ;

    const float*  qrow = qp + (size_t)(b * TQ + q0) * UU;          // wave-uniform
    const float4* kb4  = (const float4*)kT + (size_t)b * (UU / 4) * TK + t;

    float a0[RQ] = {}, a1[RQ] = {};   // split accumulators
    float4 kv = kb4[0];

    #pragma unroll 2
    for (int g = 0; g < UU / 4 - 1; g++) {
        const float4 kn  = kb4[(size_t)(g + 1) * TK];   // prefetch next
        const float4 sc4 = *(const float4*)&scale[4 * g];
        float4 q4[RQ];
        #pragma unroll
        for (int r = 0; r < RQ; r++)
            q4[r] = *(const float4*)&qrow[(size_t)r * UU + 4 * g];
        #pragma unroll
        for (int r = 0; r < RQ; r++) {
            const float* qf = (const float*)&q4[r];
            const float* sf = (const float*)&sc4;
            const float* kf = (const float*)&kv;
            a0[r] = fmaf(sf[0], frcp(fmaf(-0.5f, fexp2(qf[0] + kf[0]), -0.5f)), a0[r]);
            a1[r] = fmaf(sf[1], frcp(fmaf(-0.5f, fexp2(qf[1] + kf[1]), -0.5f)), a1[r]);
            a0[r] = fmaf(sf[2], frcp(fmaf(-0.5f, fexp2(qf[2] + kf[2]), -0.5f)), a0[r]);
            a1[r] = fmaf(sf[3], frcp(fmaf(-0.5f, fexp2(qf[3] + kf[3]), -0.5f)), a1[r]);
        }
        kv = kn;
    }
    {   // peeled last group
        const int g = UU / 4 - 1;
        const float4 sc4 = *(const float4*)&scale[4 * g];
        #pragma unroll
        for (int r = 0; r < RQ; r++) {
            float4 q4 = *(const float4*)&qrow[(size_t)r * UU + 4 * g];
            const float* qf = (const float*)&q4;
            const float* sf = (const float*)&sc4;
            const float* kf = (const float*)&kv;
            a0[r] = fmaf(sf[0], frcp(fmaf(-0.5f, fexp2(qf[0] + kf[0]), -0.5f)), a0[r]);
            a1[r] = fmaf(sf[1], frcp(fmaf(-0.5f, fexp2(qf[1] + kf[1]), -0.5f)), a1[r]);
            a0[r] = fmaf(sf[2], frcp(fmaf(-0.5f, fexp2(qf[2] + kf[2]), -0.5f)), a0[r]);
            a1[r] = fmaf(sf[3], frcp(fmaf(-0.5f, fexp2(qf[3] + kf[3]), -0.5f)), a1[r]);
        }
    }

    const int wave = t >> 6, lane = t & 63;
    float s[RQ], m[RQ], p[RQ];
    #pragma unroll
    for (int r = 0; r < RQ; r++) s[r] = a0[r] + a1[r];

    // row max over 512 threads
    #pragma unroll
    for (int r = 0; r < RQ; r++) {
        float v = s[r];
        #pragma unroll
        for (int o = 32; o > 0; o >>= 1) v = fmaxf(v, __shfl_xor(v, o));
        if (lane == 0) redbuf[r][wave] = v;
    }
    __syncthreads();
    #pragma unroll
    for (int r = 0; r < RQ; r++) {
        float v = redbuf[r][0];
        #pragma unroll
        for (int w = 1; w < 8; w++) v = fmaxf(v, redbuf[r][w]);
        m[r] = v;
    }
    __syncthreads();

    // exp and row sum
    #pragma unroll
    for (int r = 0; r < RQ; r++) {
        p[r] = fexp2(L2E * (s[r] - m[r]));
        float v = p[r];
        #pragma unroll
        for (int o = 32; o > 0; o >>= 1) v += __shfl_xor(v, o);
        if (lane == 0) redbuf[r][wave] = v;
    }
    __syncthreads();
    #pragma unroll
    for (int r = 0; r < RQ; r++) {
        float v = 0.0f;
        #pragma unroll
        for (int w = 0; w < 8; w++) v += redbuf[r][w];
        const float rinv = frcp(v);
        out[(size_t)(b * TQ + q0 + r) * TK + t] = p[r] * rinv;
    }
}

extern "C" void kernel_launch(void* const* d_in, const int* in_sizes, int n_in,
                              void* d_out, int out_size, void* d_ws, size_t ws_size,
                              hipStream_t stream) {
    const float* query = (const float*)d_in[0];
    const float* value = (const float*)d_in[1];
    const float* W1    = (const float*)d_in[2];
    const float* W2    = (const float*)d_in[3];
    const float* scale = (const float*)d_in[4];
    float* out = (float*)d_out;

    float* qp = (float*)d_ws;                     // [BB,TQ,UU]        2 MB
    float* kT = qp + (size_t)BB * TQ * UU;        // [BB,UU/4,TK] f4   2 MB

    proj<<<dim3((BB * TQ) / 8, 1, 2), dim3(256, 2), 0, stream>>>(query, value, W1, W2, qp, kT);
    attn_softmax<<<dim3(BB * TQ / RQ), 512, 0, stream>>>(qp, kT, scale, out);
}